// Round 4
// baseline (1522.353 us; speedup 1.0000x reference)
//
#include <hip/hip_runtime.h>
#include <hip/hip_cooperative_groups.h>
#include <hip/hip_bf16.h>

namespace cg = cooperative_groups;

#define N_NODES 50000
#define N_EDGES 800000
#define D 256
#define DEPTH 10
#define PAD_CAP 48
#define CHAIN_BLOCKS 16

// ws layout (4-byte units):
//   cnt    [50048]           (memset 0 per call)
//   bar    [64]              (memset 0 per call)
//   slots  [N_NODES*PAD_CAP]
//   uA     [256], uB [256]
//   cbuf   [16]   (cbuf[1..10])
//   ya     [50048], yb [50048]

__global__ __launch_bounds__(256, 4) void gcn_coop_kernel(
    const float* __restrict__ feat, const int* __restrict__ src, const int* __restrict__ dst,
    const float* __restrict__ W_in, const float* __restrict__ b_in,
    const float* __restrict__ Ws, const float* __restrict__ bsv,
    const float* __restrict__ W_out, const float* __restrict__ b_out,
    float* __restrict__ out, float* __restrict__ ws)
{
    cg::grid_group grid = cg::this_grid();

    int*   cnt   = (int*)ws;
    int*   bar   = (int*)ws + 50048;
    int*   slots = bar + 64;
    float* uA    = (float*)(slots + (size_t)N_NODES * PAD_CAP);
    float* uB    = uA + 256;
    float* cbuf  = uB + 256;
    float* ya    = cbuf + 16;
    float* yb    = ya + 50048;

    const int t       = threadIdx.x;
    const int gtid    = blockIdx.x * 256 + t;
    const int nthreads = gridDim.x * 256;

    __shared__ float sh[2048];

    // ---------- phase 1: chain (blocks 0..15)  ||  scatter (blocks 16..) ----------
    if (blockIdx.x < CHAIN_BLOCKS) {
        const int wave = t >> 6, lane = t & 63;
        const int rbase = blockIdx.x * 16 + wave * 4;   // 4 rows per wave, 16 rows per block
        for (int s = 0; s < DEPTH; ++s) {
            const int j = DEPTH - s;                    // layer 10..1
            const float* uin = (s == 0) ? W_out : ((s & 1) ? uA : uB);
            float* uout = (s & 1) ? uB : uA;
            float u0, u1, u2, u3;
            if (s == 0) {
                u0 = uin[lane * 4];     u1 = uin[lane * 4 + 1];
                u2 = uin[lane * 4 + 2]; u3 = uin[lane * 4 + 3];
            } else {   // written by other blocks via agent-scope atomic stores
                u0 = __hip_atomic_load(uin + lane * 4,     __ATOMIC_ACQUIRE, __HIP_MEMORY_SCOPE_AGENT);
                u1 = __hip_atomic_load(uin + lane * 4 + 1, __ATOMIC_ACQUIRE, __HIP_MEMORY_SCOPE_AGENT);
                u2 = __hip_atomic_load(uin + lane * 4 + 2, __ATOMIC_ACQUIRE, __HIP_MEMORY_SCOPE_AGENT);
                u3 = __hip_atomic_load(uin + lane * 4 + 3, __ATOMIC_ACQUIRE, __HIP_MEMORY_SCOPE_AGENT);
            }
#pragma unroll
            for (int rr = 0; rr < 4; ++rr) {
                const float* wrow = Ws + (size_t)(j - 1) * D * D + (size_t)(rbase + rr) * D + lane * 4;
                float4 w4 = *reinterpret_cast<const float4*>(wrow);
                float p = w4.x * u0 + w4.y * u1 + w4.z * u2 + w4.w * u3;
                for (int off = 32; off > 0; off >>= 1) p += __shfl_down(p, off);
                if (lane == 0)
                    __hip_atomic_store(uout + rbase + rr, p, __ATOMIC_RELEASE, __HIP_MEMORY_SCOPE_AGENT);
            }
            if (blockIdx.x == 0 && wave == 3) {         // c_j = bs[j-1] . u_j
                const float* brow = bsv + (size_t)(j - 1) * D + lane * 4;
                float4 b4 = *reinterpret_cast<const float4*>(brow);
                float p = b4.x * u0 + b4.y * u1 + b4.z * u2 + b4.w * u3;
                for (int off = 32; off > 0; off >>= 1) p += __shfl_down(p, off);
                if (lane == 0) cbuf[j] = p;             // consumed only after grid.sync()
            }
            // barrier among the 16 chain blocks (monotone counter, all blocks resident)
            __syncthreads();
            if (t == 0) {
                __hip_atomic_fetch_add(bar, 1, __ATOMIC_ACQ_REL, __HIP_MEMORY_SCOPE_AGENT);
                const int target = CHAIN_BLOCKS * (s + 1);
                while (__hip_atomic_load(bar, __ATOMIC_ACQUIRE, __HIP_MEMORY_SCOPE_AGENT) < target)
                    __builtin_amdgcn_s_sleep(2);
            }
            __syncthreads();
        }
    } else {
        const int stid = (blockIdx.x - CHAIN_BLOCKS) * 256 + t;
        const int sstr = (gridDim.x - CHAIN_BLOCKS) * 256;
        for (int e = stid; e < N_EDGES; e += sstr) {
            int d = dst[e];
            int pos = atomicAdd(&cnt[d], 1);
            if (pos < PAD_CAP) slots[(size_t)d * PAD_CAP + pos] = src[e];
        }
    }
    grid.sync();

    // ---------- phase 2: y0[i] = sum_d relu(b_in + agg6 . W_in)[d] * u0[d] ----------
    {
        float* Wsh = sh;            // 1536
        float* bsh = sh + 1536;     // 256
        float* ush = sh + 1792;     // 256
        for (int i = t; i < 1536; i += 256) Wsh[i] = W_in[i];
        bsh[t] = b_in[t];
        ush[t] = uB[t];             // u_0 lands in uB after 10 ping-pong steps
        __syncthreads();
        for (int node = gtid; node < N_NODES; node += nthreads) {
            int c = cnt[node]; if (c > PAD_CAP) c = PAD_CAP;
            const int* sl = slots + (size_t)node * PAD_CAP;
            float f0 = 0, f1 = 0, f2 = 0, f3 = 0, f4 = 0, f5 = 0;
            for (int jj = 0; jj < c; ++jj) {
                const float* fr = feat + (size_t)sl[jj] * 6;
                float2 a  = *reinterpret_cast<const float2*>(fr);
                float2 b2 = *reinterpret_cast<const float2*>(fr + 2);
                float2 cc = *reinterpret_cast<const float2*>(fr + 4);
                f0 += a.x; f1 += a.y; f2 += b2.x; f3 += b2.y; f4 += cc.x; f5 += cc.y;
            }
            float sacc = 0.f;
#pragma unroll 4
            for (int d2 = 0; d2 < D; ++d2) {
                float pre = bsh[d2]
                          + f0 * Wsh[d2]        + f1 * Wsh[256 + d2]  + f2 * Wsh[512 + d2]
                          + f3 * Wsh[768 + d2]  + f4 * Wsh[1024 + d2] + f5 * Wsh[1280 + d2];
                sacc += fmaxf(pre, 0.f) * ush[d2];
            }
            ya[node] = sacc;
        }
    }
    grid.sync();

    // ---------- phase 3: 10 scalar propagations + final into out ----------
    const int g4 = gtid >> 2, lane4 = gtid & 3, gstr = nthreads >> 2;
    float* cur = ya;
    float* nxt = yb;
    for (int k = 1; k <= DEPTH; ++k) {
        const float ck = cbuf[k];
        for (int node = g4; node < N_NODES; node += gstr) {
            int c = cnt[node]; if (c > PAD_CAP) c = PAD_CAP;
            const int* sl = slots + (size_t)node * PAD_CAP;
            float p = 0.f;
            for (int jj = lane4; jj < c; jj += 4) p += cur[sl[jj]];
            p += __shfl_xor(p, 1);
            p += __shfl_xor(p, 2);
            if (lane4 == 0) nxt[node] = ck + p;
        }
        grid.sync();
        float* tmp = cur; cur = nxt; nxt = tmp;
    }
    {
        const float bo = b_out[0];
        for (int node = g4; node < N_NODES; node += gstr) {
            int c = cnt[node]; if (c > PAD_CAP) c = PAD_CAP;
            const int* sl = slots + (size_t)node * PAD_CAP;
            float p = 0.f;
            for (int jj = lane4; jj < c; jj += 4) p += cur[sl[jj]];
            p += __shfl_xor(p, 1);
            p += __shfl_xor(p, 2);
            if (lane4 == 0) out[node] = bo + p;
        }
    }
}

// ---------------- launch ----------------

extern "C" void kernel_launch(void* const* d_in, const int* in_sizes, int n_in,
                              void* d_out, int out_size, void* d_ws, size_t ws_size,
                              hipStream_t stream) {
    const float* feat  = (const float*)d_in[0];
    const int*   src   = (const int*)d_in[1];
    const int*   dst   = (const int*)d_in[2];
    const float* W_in  = (const float*)d_in[3];
    const float* b_in  = (const float*)d_in[4];
    const float* Ws    = (const float*)d_in[5];
    const float* bsv   = (const float*)d_in[6];
    const float* W_out = (const float*)d_in[7];
    const float* b_out = (const float*)d_in[8];
    float* out = (float*)d_out;
    float* ws  = (float*)d_ws;

    // co-resident grid size: blocks/CU from occupancy query x 256 CUs, capped at 1024
    int maxPerCU = 0;
    (void)hipOccupancyMaxActiveBlocksPerMultiprocessor(&maxPerCU, gcn_coop_kernel, 256, 0);
    int grid = maxPerCU * 256;
    if (grid > 1024) grid = 1024;
    if (grid < 64)  grid = 64;

    // zero cnt + bar (everything else is write-before-read)
    (void)hipMemsetAsync(d_ws, 0, (size_t)(50048 + 64) * 4, stream);

    void* kargs[] = {
        (void*)&feat, (void*)&src, (void*)&dst, (void*)&W_in, (void*)&b_in,
        (void*)&Ws, (void*)&bsv, (void*)&W_out, (void*)&b_out,
        (void*)&out, (void*)&ws
    };
    (void)hipLaunchCooperativeKernel(gcn_coop_kernel, dim3(grid), dim3(256),
                                     kargs, 0, stream);
}

// Round 5
// 227.077 us; speedup vs baseline: 6.7041x; 6.7041x over previous
//
#include <hip/hip_runtime.h>
#include <hip/hip_bf16.h>

#define N_NODES 50000
#define N_EDGES 800000
#define D 256
#define DEPTH 10
#define PAD_CAP 48
#define CHAIN_BLOCKS 32
#define EG ((N_EDGES + 255) / 256)   // 3125

// ws layout (4-byte units):
//   cnt[50048], bar[64], slots[N_NODES*PAD_CAP],
//   uA[256], uB[256], cbuf[16], ya[50048], yb[50048]

// ---------- kernel A: chain (blocks 0..31) || padded scatter (blocks 32..) ----------
__global__ __launch_bounds__(256) void build_chain_kernel(
    const int* __restrict__ src, const int* __restrict__ dst,
    const float* __restrict__ Ws, const float* __restrict__ bsv,
    const float* __restrict__ W_out,
    int* __restrict__ cnt, int* __restrict__ bar, int* __restrict__ slots,
    float* __restrict__ uA, float* __restrict__ uB, float* __restrict__ cbuf)
{
    const int t = threadIdx.x;
    if (blockIdx.x < CHAIN_BLOCKS) {
        // 32 blocks x 4 waves; each wave owns 2 rows of the 256-row matvec.
        const int wave = t >> 6, lane = t & 63;
        const int rbase = blockIdx.x * 8 + wave * 2;
        for (int s = 0; s < DEPTH; ++s) {
            const int j = DEPTH - s;                       // layer 10..1
            const float* uin = (s == 0) ? W_out : ((s & 1) ? uA : uB);
            float* uout = (s & 1) ? uB : uA;
            float u0, u1, u2, u3;
            if (s == 0) {
                u0 = uin[lane * 4];     u1 = uin[lane * 4 + 1];
                u2 = uin[lane * 4 + 2]; u3 = uin[lane * 4 + 3];
            } else {
                u0 = __hip_atomic_load(uin + lane * 4,     __ATOMIC_ACQUIRE, __HIP_MEMORY_SCOPE_AGENT);
                u1 = __hip_atomic_load(uin + lane * 4 + 1, __ATOMIC_ACQUIRE, __HIP_MEMORY_SCOPE_AGENT);
                u2 = __hip_atomic_load(uin + lane * 4 + 2, __ATOMIC_ACQUIRE, __HIP_MEMORY_SCOPE_AGENT);
                u3 = __hip_atomic_load(uin + lane * 4 + 3, __ATOMIC_ACQUIRE, __HIP_MEMORY_SCOPE_AGENT);
            }
#pragma unroll
            for (int rr = 0; rr < 2; ++rr) {
                const int r = rbase + rr;
                float4 w4 = *reinterpret_cast<const float4*>(
                    Ws + (size_t)(j - 1) * D * D + (size_t)r * D + lane * 4);
                float p = w4.x * u0 + w4.y * u1 + w4.z * u2 + w4.w * u3;
                for (int off = 32; off > 0; off >>= 1) p += __shfl_down(p, off);
                if (lane == 0)
                    __hip_atomic_store(uout + r, p, __ATOMIC_RELEASE, __HIP_MEMORY_SCOPE_AGENT);
            }
            if (blockIdx.x == 0 && wave == 3) {            // c_j = bs[j-1] . u_j
                float4 b4 = *reinterpret_cast<const float4*>(bsv + (size_t)(j - 1) * D + lane * 4);
                float p = b4.x * u0 + b4.y * u1 + b4.z * u2 + b4.w * u3;
                for (int off = 32; off > 0; off >>= 1) p += __shfl_down(p, off);
                if (lane == 0) cbuf[j] = p;                // consumed after kernel boundary
            }
            // private barrier among the 32 chain blocks (monotone counter)
            __syncthreads();
            if (t == 0) {
                __hip_atomic_fetch_add(bar, 1, __ATOMIC_ACQ_REL, __HIP_MEMORY_SCOPE_AGENT);
                const int target = CHAIN_BLOCKS * (s + 1);
                while (__hip_atomic_load(bar, __ATOMIC_ACQUIRE, __HIP_MEMORY_SCOPE_AGENT) < target)
                    __builtin_amdgcn_s_sleep(2);
            }
            __syncthreads();
        }
    } else {
        const int e = (blockIdx.x - CHAIN_BLOCKS) * 256 + t;
        if (e < N_EDGES) {
            int d = dst[e];
            int pos = atomicAdd(&cnt[d], 1);
            if (pos < PAD_CAP) slots[(size_t)d * PAD_CAP + pos] = src[e];
        }
    }
}

// ---------- y0[i] = sum_d relu(b_in + agg6 . W_in)[d] * u0[d] ----------
__global__ __launch_bounds__(256) void y0_kernel(const float* __restrict__ feat,
                                                 const int* __restrict__ cnt,
                                                 const int* __restrict__ slots,
                                                 const float* __restrict__ W_in,
                                                 const float* __restrict__ b_in,
                                                 const float* __restrict__ u0v,
                                                 float* __restrict__ y0) {
    __shared__ float Wsh[6 * D];
    __shared__ float bsh[D];
    __shared__ float ush[D];
    const int t = threadIdx.x;
    for (int i = t; i < 6 * D; i += 256) Wsh[i] = W_in[i];
    bsh[t] = b_in[t];
    ush[t] = u0v[t];
    __syncthreads();
    const int node = blockIdx.x * 256 + t;
    if (node >= N_NODES) return;
    int c = cnt[node]; if (c > PAD_CAP) c = PAD_CAP;
    const int* sl = slots + (size_t)node * PAD_CAP;
    float f0 = 0, f1 = 0, f2 = 0, f3 = 0, f4 = 0, f5 = 0;
    const int g4 = c >> 2;
    for (int g = 0; g < g4; ++g) {
        int4 v = reinterpret_cast<const int4*>(sl)[g];
        int idx[4] = {v.x, v.y, v.z, v.w};
#pragma unroll
        for (int e = 0; e < 4; ++e) {
            const float* fr = feat + (size_t)idx[e] * 6;
            float2 a  = *reinterpret_cast<const float2*>(fr);
            float2 b2 = *reinterpret_cast<const float2*>(fr + 2);
            float2 cc = *reinterpret_cast<const float2*>(fr + 4);
            f0 += a.x; f1 += a.y; f2 += b2.x; f3 += b2.y; f4 += cc.x; f5 += cc.y;
        }
    }
    for (int jj = g4 * 4; jj < c; ++jj) {
        const float* fr = feat + (size_t)sl[jj] * 6;
        float2 a  = *reinterpret_cast<const float2*>(fr);
        float2 b2 = *reinterpret_cast<const float2*>(fr + 2);
        float2 cc = *reinterpret_cast<const float2*>(fr + 4);
        f0 += a.x; f1 += a.y; f2 += b2.x; f3 += b2.y; f4 += cc.x; f5 += cc.y;
    }
    float s = 0.f;
#pragma unroll 4
    for (int d2 = 0; d2 < D; ++d2) {
        float pre = bsh[d2]
                  + f0 * Wsh[d2]       + f1 * Wsh[256 + d2]  + f2 * Wsh[512 + d2]
                  + f3 * Wsh[768 + d2] + f4 * Wsh[1024 + d2] + f5 * Wsh[1280 + d2];
        s += fmaxf(pre, 0.f) * ush[d2];
    }
    y0[node] = s;
}

// ---------- prop: 2 threads per node, int4 slot loads ----------
__global__ __launch_bounds__(256) void prop2_kernel(const float* __restrict__ yin,
                                                    float* __restrict__ yout,
                                                    const int* __restrict__ cnt,
                                                    const int* __restrict__ slots,
                                                    const float* __restrict__ cptr) {
    const int gid = blockIdx.x * 256 + threadIdx.x;
    const int node = gid >> 1, half = gid & 1;
    if (node >= N_NODES) return;
    int c = cnt[node]; if (c > PAD_CAP) c = PAD_CAP;
    const int* sl = slots + (size_t)node * PAD_CAP;
    float p = 0.f;
    const int g4 = c >> 2;
    for (int g = half; g < g4; g += 2) {
        int4 v = reinterpret_cast<const int4*>(sl)[g];
        p += yin[v.x] + yin[v.y] + yin[v.z] + yin[v.w];
    }
    if (half == 0)
        for (int jj = g4 * 4; jj < c; ++jj) p += yin[sl[jj]];
    p += __shfl_xor(p, 1);
    if (half == 0) yout[node] = cptr[0] + p;
}

// ---------------- launch ----------------

extern "C" void kernel_launch(void* const* d_in, const int* in_sizes, int n_in,
                              void* d_out, int out_size, void* d_ws, size_t ws_size,
                              hipStream_t stream) {
    const float* feat  = (const float*)d_in[0];
    const int*   src   = (const int*)d_in[1];
    const int*   dst   = (const int*)d_in[2];
    const float* W_in  = (const float*)d_in[3];
    const float* b_in  = (const float*)d_in[4];
    const float* Ws    = (const float*)d_in[5];
    const float* bsv   = (const float*)d_in[6];
    const float* W_out = (const float*)d_in[7];
    const float* b_out = (const float*)d_in[8];
    float* out = (float*)d_out;

    int*   cnt   = (int*)d_ws;                                   // 50048
    int*   bar   = cnt + 50048;                                  // 64
    int*   slots = bar + 64;                                     // 50000*48
    float* uA    = (float*)(slots + (size_t)N_NODES * PAD_CAP);  // 256
    float* uB    = uA + 256;                                     // 256
    float* cbuf  = uB + 256;                                     // 16
    float* ya    = cbuf + 16;                                    // 50048
    float* yb    = ya + 50048;                                   // 50048

    const int B = 256;
    const int NG = (N_NODES + B - 1) / B;            // 196
    const int PG = (2 * N_NODES + B - 1) / B;        // 391

    (void)hipMemsetAsync(d_ws, 0, (size_t)(50048 + 64) * 4, stream);

    build_chain_kernel<<<EG + CHAIN_BLOCKS, B, 0, stream>>>(
        src, dst, Ws, bsv, W_out, cnt, bar, slots, uA, uB, cbuf);

    // u_0 ends in uB after 10 ping-pong steps
    y0_kernel<<<NG, B, 0, stream>>>(feat, cnt, slots, W_in, b_in, uB, ya);

    float* cur = ya;
    float* nxt = yb;
    for (int k = 1; k <= DEPTH; ++k) {
        prop2_kernel<<<PG, B, 0, stream>>>(cur, nxt, cnt, slots, cbuf + k);
        float* tmp = cur; cur = nxt; nxt = tmp;
    }
    prop2_kernel<<<PG, B, 0, stream>>>(cur, out, cnt, slots, b_out);
}

// Round 6
// 215.878 us; speedup vs baseline: 7.0519x; 1.0519x over previous
//
#include <hip/hip_runtime.h>
#include <hip/hip_bf16.h>

#define N_NODES 50000
#define N_EDGES 800000
#define D 256
#define DEPTH 10
#define PAD_CAP 48
#define CHAIN_BLOCKS 32
#define SENTINEL 50000
#define EG ((N_EDGES + 255) / 256)   // 3125

// ws layout (4-byte units):
//   cnt[50048], slots[N_NODES*PAD_CAP], u0g[256], cbuf[16], ya[50048], yb[50048]

// ---------- kernel A: redundant barrier-free chain (blocks 0..31) || scatter ----------
__global__ __launch_bounds__(256) void build_chain_kernel(
    const int* __restrict__ src, const int* __restrict__ dst,
    const float* __restrict__ Ws, const float* __restrict__ bsv,
    const float* __restrict__ W_out,
    int* __restrict__ cnt, int* __restrict__ slots,
    float* __restrict__ u0g, float* __restrict__ cbuf)
{
    const int t = threadIdx.x;
    if (blockIdx.x < CHAIN_BLOCKS) {
        // Each block computes the ENTIRE chain redundantly (bit-identical across
        // blocks); u ping-pongs in LDS; no inter-block sync, no atomics.
        // 32 co-reading blocks warm L2/L3 for each other.
        __shared__ float u[2][D];
        __shared__ float wred[4];
        u[0][t] = W_out[t];
        __syncthreads();
        int cur = 0;
        for (int s = 0; s < DEPTH; ++s) {
            const int j = DEPTH - s;                    // layer 10..1
            // c_j = bs[j-1] . u_cur   (wave-reduce, partials to LDS)
            {
                float pc = bsv[(size_t)(j - 1) * D + t] * u[cur][t];
                for (int off = 32; off > 0; off >>= 1) pc += __shfl_down(pc, off);
                if ((t & 63) == 0) wred[t >> 6] = pc;
            }
            // u_next[t] = Ws[j-1][t,:] . u_cur
            const float* wrow = Ws + (size_t)(j - 1) * D * D + (size_t)t * D;
            float acc = 0.f;
#pragma unroll 8
            for (int k = 0; k < D; k += 4) {
                float4 w4 = *reinterpret_cast<const float4*>(wrow + k);
                acc += w4.x * u[cur][k]     + w4.y * u[cur][k + 1]
                     + w4.z * u[cur][k + 2] + w4.w * u[cur][k + 3];
            }
            __syncthreads();            // wred written; u[cur] fully consumed
            if (blockIdx.x == 0 && t == 0)
                cbuf[j] = wred[0] + wred[1] + wred[2] + wred[3];
            u[cur ^ 1][t] = acc;
            cur ^= 1;
            __syncthreads();
        }
        if (blockIdx.x == 0) u0g[t] = u[cur][t];
    } else {
        const int e = (blockIdx.x - CHAIN_BLOCKS) * 256 + t;
        if (e < N_EDGES) {
            int d = dst[e];
            int pos = atomicAdd(&cnt[d], 1);
            if (pos < PAD_CAP) slots[(size_t)d * PAD_CAP + pos] = src[e];
        }
    }
}

// ---------- y0 + slot-row sentinel fixup ----------
__global__ __launch_bounds__(256) void y0_kernel(const float* __restrict__ feat,
                                                 const int* __restrict__ cnt,
                                                 int* __restrict__ slots,
                                                 const float* __restrict__ W_in,
                                                 const float* __restrict__ b_in,
                                                 const float* __restrict__ u0v,
                                                 float* __restrict__ ya,
                                                 float* __restrict__ yb) {
    __shared__ float Wsh[6 * D];
    __shared__ float bsh[D];
    __shared__ float ush[D];
    const int t = threadIdx.x;
    for (int i = t; i < 6 * D; i += 256) Wsh[i] = W_in[i];
    bsh[t] = b_in[t];
    ush[t] = u0v[t];
    __syncthreads();
    if (blockIdx.x == 0 && t < PAD_CAP) {   // zero the sentinel target in both buffers
        ya[SENTINEL + t] = 0.f;
        yb[SENTINEL + t] = 0.f;
    }
    const int node = blockIdx.x * 256 + t;
    if (node >= N_NODES) return;
    int c = cnt[node]; if (c > PAD_CAP) c = PAD_CAP;
    int* sl = slots + (size_t)node * PAD_CAP;
    // pad row tail to multiple of 4 with SENTINEL (branch-free prop loops)
    const int cr = (c + 3) & ~3;
    for (int i = c; i < cr; ++i) sl[i] = SENTINEL;
    float f0 = 0, f1 = 0, f2 = 0, f3 = 0, f4 = 0, f5 = 0;
    for (int jj = 0; jj < c; ++jj) {
        const float* fr = feat + (size_t)sl[jj] * 6;
        float2 a  = *reinterpret_cast<const float2*>(fr);
        float2 b2 = *reinterpret_cast<const float2*>(fr + 2);
        float2 cc = *reinterpret_cast<const float2*>(fr + 4);
        f0 += a.x; f1 += a.y; f2 += b2.x; f3 += b2.y; f4 += cc.x; f5 += cc.y;
    }
    float s = 0.f;
#pragma unroll 4
    for (int d2 = 0; d2 < D; ++d2) {
        float pre = bsh[d2]
                  + f0 * Wsh[d2]       + f1 * Wsh[256 + d2]  + f2 * Wsh[512 + d2]
                  + f3 * Wsh[768 + d2] + f4 * Wsh[1024 + d2] + f5 * Wsh[1280 + d2];
        s += fmaxf(pre, 0.f) * ush[d2];
    }
    ya[node] = s;
}

// ---------- prop: 4 threads/node, branch-free int4 groups ----------
__global__ __launch_bounds__(256) void prop4_kernel(const float* __restrict__ yin,
                                                    float* __restrict__ yout,
                                                    const int* __restrict__ cnt,
                                                    const int* __restrict__ slots,
                                                    const float* __restrict__ cptr) {
    const int gid = blockIdx.x * 256 + threadIdx.x;
    const int node = gid >> 2, lane4 = gid & 3;
    if (node >= N_NODES) return;
    int c = cnt[node]; if (c > PAD_CAP) c = PAD_CAP;
    const int g4r = (c + 3) >> 2;
    const int4* sl = reinterpret_cast<const int4*>(slots + (size_t)node * PAD_CAP);
    float p = 0.f;
    for (int g = lane4; g < g4r; g += 4) {
        int4 v = sl[g];
        p += yin[v.x] + yin[v.y] + yin[v.z] + yin[v.w];
    }
    p += __shfl_xor(p, 1);
    p += __shfl_xor(p, 2);
    if (lane4 == 0) yout[node] = cptr[0] + p;
}

// ---------------- launch ----------------

extern "C" void kernel_launch(void* const* d_in, const int* in_sizes, int n_in,
                              void* d_out, int out_size, void* d_ws, size_t ws_size,
                              hipStream_t stream) {
    const float* feat  = (const float*)d_in[0];
    const int*   src   = (const int*)d_in[1];
    const int*   dst   = (const int*)d_in[2];
    const float* W_in  = (const float*)d_in[3];
    const float* b_in  = (const float*)d_in[4];
    const float* Ws    = (const float*)d_in[5];
    const float* bsv   = (const float*)d_in[6];
    const float* W_out = (const float*)d_in[7];
    const float* b_out = (const float*)d_in[8];
    float* out = (float*)d_out;

    int*   cnt   = (int*)d_ws;                                   // 50048
    int*   slots = cnt + 50048;                                  // 50000*48 (16B-aligned)
    float* u0g   = (float*)(slots + (size_t)N_NODES * PAD_CAP);  // 256
    float* cbuf  = u0g + 256;                                    // 16
    float* ya    = cbuf + 16;                                    // 50048
    float* yb    = ya + 50048;                                   // 50048

    const int B = 256;
    const int NG = (N_NODES + B - 1) / B;            // 196
    const int PG = (4 * N_NODES + B - 1) / B;        // 782

    (void)hipMemsetAsync(cnt, 0, (size_t)50048 * 4, stream);

    build_chain_kernel<<<EG + CHAIN_BLOCKS, B, 0, stream>>>(
        src, dst, Ws, bsv, W_out, cnt, slots, u0g, cbuf);

    y0_kernel<<<NG, B, 0, stream>>>(feat, cnt, slots, W_in, b_in, u0g, ya, yb);

    float* cur = ya;
    float* nxt = yb;
    for (int k = 1; k <= DEPTH; ++k) {
        prop4_kernel<<<PG, B, 0, stream>>>(cur, nxt, cnt, slots, cbuf + k);
        float* tmp = cur; cur = nxt; nxt = tmp;
    }
    prop4_kernel<<<PG, B, 0, stream>>>(cur, out, cnt, slots, b_out);
}